// Round 1
// baseline (670.652 us; speedup 1.0000x reference)
//
#include <hip/hip_runtime.h>
#include <stdint.h>

#define C_ 1024
#define K_ 16
#define S_ 32
#define Y_ 128
#define N_ (C_ * K_)          // 16384 cells
#define ACT_THR 10
#define PERM_THR 0.5f
#define POT 0.1f              // LR * MOD
#define PUN 0.01f             // POT * 0.1

// ---- workspace layout (u32 indices) ----
#define WS_NUM_ACTIVE 0
#define WS_NUM_PRED   1
#define WS_NBURST     2
#define WS_LEARN_CNT  3
#define WS_PREV_ANY   4
#define WS_BURSTMASK  8        // 32 words  (1024 column bits)
#define WS_PREVMASK   64       // 512 words (16384 cell bits)
#define WS_CELLINFO   1024     // N words: pred(1b) | best_seg<<8 | best_overlap<<16
#define WS_LIST       (1024 + N_) // up to N winner-cell ids

// ---------------------------------------------------------------------------
// Kernel 1: pack prev_active bits into ws bitmask, zero counters, prev_any.
// ---------------------------------------------------------------------------
__global__ __launch_bounds__(256) void pack_kernel(const int* __restrict__ prev,
                                                   unsigned* __restrict__ ws) {
    const int tid = threadIdx.x;
    if (tid < 64) ws[tid] = 0u;   // counters + burst mask
    __syncthreads();
    bool any = false;
    for (int w = tid; w < 512; w += 256) {
        unsigned m = 0u;
        #pragma unroll
        for (int b = 0; b < 32; ++b) {
            if (prev[w * 32 + b] != 0) m |= (1u << b);
        }
        ws[WS_PREVMASK + w] = m;
        any |= (m != 0u);
    }
    if (any) atomicOr(&ws[WS_PREV_ANY], 1u);
}

// ---------------------------------------------------------------------------
// Kernel 2: phase 1 — per-segment active-synapse count + overlap.
// One block per cell. 4 waves; each wave handles 8 segments, two at a time
// (half-wave per segment, 4 synapses per lane, 16B vector loads).
// ---------------------------------------------------------------------------
__global__ __launch_bounds__(256) void phase1_kernel(const int*   __restrict__ conn,
                                                     const float* __restrict__ vol,
                                                     const float* __restrict__ cons,
                                                     unsigned*    __restrict__ ws) {
    __shared__ unsigned prevmask[512];
    __shared__ int sA[S_];
    __shared__ int sO[S_];
    const int tid = threadIdx.x;
    for (int i = tid; i < 512; i += 256) prevmask[i] = ws[WS_PREVMASK + i];
    __syncthreads();

    const int cell = blockIdx.x;
    const int wave = tid >> 6;
    const int lane = tid & 63;
    const int half = lane >> 5;
    const int l32  = lane & 31;
    const int sh   = half * 32;

    #pragma unroll
    for (int t = 0; t < 4; ++t) {
        const int seg = wave * 8 + t * 2 + half;
        const size_t base = ((size_t)cell * S_ + seg) * Y_ + (size_t)(l32 * 4);
        const int4   cv = *reinterpret_cast<const int4*>(conn + base);
        const float4 vv = *reinterpret_cast<const float4*>(vol + base);
        const float4 sv = *reinterpret_cast<const float4*>(cons + base);

        const int m0 = min(max(cv.x, 0), N_ - 1);
        const int m1 = min(max(cv.y, 0), N_ - 1);
        const int m2 = min(max(cv.z, 0), N_ - 1);
        const int m3 = min(max(cv.w, 0), N_ - 1);
        const bool p0 = (prevmask[m0 >> 5] >> (m0 & 31)) & 1u;
        const bool p1 = (prevmask[m1 >> 5] >> (m1 & 31)) & 1u;
        const bool p2 = (prevmask[m2 >> 5] >> (m2 & 31)) & 1u;
        const bool p3 = (prevmask[m3 >> 5] >> (m3 & 31)) & 1u;
        const bool c0 = (vv.x > PERM_THR) || (sv.x > PERM_THR);
        const bool c1 = (vv.y > PERM_THR) || (sv.y > PERM_THR);
        const bool c2 = (vv.z > PERM_THR) || (sv.z > PERM_THR);
        const bool c3 = (vv.w > PERM_THR) || (sv.w > PERM_THR);

        const uint64_t bp0 = __ballot(p0), bp1 = __ballot(p1),
                       bp2 = __ballot(p2), bp3 = __ballot(p3);
        const uint64_t ba0 = __ballot(p0 && c0), ba1 = __ballot(p1 && c1),
                       ba2 = __ballot(p2 && c2), ba3 = __ballot(p3 && c3);

        const int ov = __popc((unsigned)(bp0 >> sh)) + __popc((unsigned)(bp1 >> sh)) +
                       __popc((unsigned)(bp2 >> sh)) + __popc((unsigned)(bp3 >> sh));
        const int ac = __popc((unsigned)(ba0 >> sh)) + __popc((unsigned)(ba1 >> sh)) +
                       __popc((unsigned)(ba2 >> sh)) + __popc((unsigned)(ba3 >> sh));
        if (l32 == 0) { sO[seg] = ov; sA[seg] = ac; }
    }
    __syncthreads();
    if (tid == 0) {
        bool pred = false;
        int bo = -1, bs = 0;
        #pragma unroll
        for (int s = 0; s < S_; ++s) {
            pred |= (sA[s] >= ACT_THR);
            if (sO[s] > bo) { bo = sO[s]; bs = s; }   // first-max (jnp.argmax)
        }
        ws[WS_CELLINFO + cell] = (pred ? 1u : 0u) | ((unsigned)bs << 8) | ((unsigned)bo << 16);
    }
}

// ---------------------------------------------------------------------------
// Kernel 3: per-column logic — predicted / burst winner / new_active output,
// learn list, counters, burst-column bitmask.
// ---------------------------------------------------------------------------
__global__ __launch_bounds__(256) void column_kernel(const int* __restrict__ x,
                                                     unsigned*  __restrict__ ws,
                                                     float*     __restrict__ out_new_active) {
    const int c = blockIdx.x * 256 + threadIdx.x;
    if (c >= C_) return;
    const bool xa = (x[c] != 0);
    const int base = c * K_;

    unsigned info[K_];
    bool colpred = false;
    int bo = -1, bk = 0;
    #pragma unroll
    for (int k = 0; k < K_; ++k) {
        const unsigned inf = ws[WS_CELLINFO + base + k];
        info[k] = inf;
        if (inf & 1u) colpred = true;
        const int ov = (int)((inf >> 16) & 0xFFu);
        if (ov > bo) { bo = ov; bk = k; }   // strict > keeps first (k,s) flat argmax
    }

    const bool burst = xa && !colpred;
    const float nav = burst ? 1.0f : 0.0f;
    #pragma unroll
    for (int k = 0; k < K_; ++k) out_new_active[base + k] = nav;

    if (xa) {
        atomicAdd(&ws[WS_NUM_ACTIVE], 1u);
        if (colpred) atomicAdd(&ws[WS_NUM_PRED], 1u);
    }
    if (burst) {
        atomicAdd(&ws[WS_NBURST], 1u);
        atomicOr(&ws[WS_BURSTMASK + (c >> 5)], 1u << (c & 31));
    }
    // winners (learning rows): predicted cells in predicted active columns,
    // else the burst winner cell in bursting active columns.
    if (xa) {
        if (colpred) {
            #pragma unroll
            for (int k = 0; k < K_; ++k) {
                if (info[k] & 1u) {
                    const unsigned i = atomicAdd(&ws[WS_LEARN_CNT], 1u);
                    ws[WS_LIST + i] = (unsigned)(base + k);
                }
            }
        } else {
            const unsigned i = atomicAdd(&ws[WS_LEARN_CNT], 1u);
            ws[WS_LIST + i] = (unsigned)(base + bk);
        }
    }
}

// ---------------------------------------------------------------------------
// Kernel 4: learning — update volatile permanences on each winner's best
// segment (in place; harness restores inputs before every launch). Also
// writes acc.
// ---------------------------------------------------------------------------
__global__ __launch_bounds__(256) void learn_kernel(const int* __restrict__ conn,
                                                    float*     __restrict__ vol,
                                                    unsigned*  __restrict__ ws,
                                                    float*     __restrict__ out_acc) {
    __shared__ unsigned prevmask[512];
    const int tid = threadIdx.x;
    for (int i = tid; i < 512; i += 256) prevmask[i] = ws[WS_PREVMASK + i];
    __syncthreads();

    if (blockIdx.x == 0 && tid == 0) {
        const int na  = (int)ws[WS_NUM_ACTIVE];
        const int np_ = (int)ws[WS_NUM_PRED];
        out_acc[0] = (na > 0) ? ((float)np_ / (float)na) : 1.0f;
    }
    if (ws[WS_PREV_ANY] == 0u) return;   // torch skips learning if no prev activity

    const int cnt    = (int)ws[WS_LEARN_CNT];
    const int wave   = (blockIdx.x * 256 + tid) >> 6;
    const int lane   = tid & 63;
    const int nwaves = gridDim.x * 4;

    for (int e = wave; e < cnt; e += nwaves) {
        const int cell = (int)ws[WS_LIST + e];
        const int seg  = (int)((ws[WS_CELLINFO + cell] >> 8) & 0xFFu);
        const size_t base = ((size_t)cell * S_ + seg) * Y_ + (size_t)(lane * 2);
        const int2 cv = *reinterpret_cast<const int2*>(conn + base);
        float2 vv = *reinterpret_cast<const float2*>(vol + base);
        const int m0 = min(max(cv.x, 0), N_ - 1);
        const int m1 = min(max(cv.y, 0), N_ - 1);
        const bool p0 = (prevmask[m0 >> 5] >> (m0 & 31)) & 1u;
        const bool p1 = (prevmask[m1 >> 5] >> (m1 & 31)) & 1u;
        vv.x = fminf(fmaxf(vv.x + (p0 ? POT : -PUN), 0.0f), 1.0f);
        vv.y = fminf(fmaxf(vv.y + (p1 ? POT : -PUN), 0.0f), 1.0f);
        *reinterpret_cast<float2*>(vol + base) = vv;
    }
}

// ---------------------------------------------------------------------------
// Kernel 5: phase 2 — predictive state for next step from new active cells
// (which are column-broadcast: new_active_flat[m] = burst[col(m)]) and the
// updated permanences. Early-exits to zeros when no column bursts.
// ---------------------------------------------------------------------------
__global__ __launch_bounds__(256) void phase2_kernel(const int*   __restrict__ conn,
                                                     const float* __restrict__ vol,
                                                     const float* __restrict__ cons,
                                                     const unsigned* __restrict__ ws,
                                                     float* __restrict__ out_pred_next) {
    const int cell = blockIdx.x;
    const int tid  = threadIdx.x;
    if (ws[WS_NBURST] == 0u) {          // uniform across the whole grid
        if (tid == 0) out_pred_next[cell] = 0.0f;
        return;
    }
    __shared__ unsigned burstmask[32];
    __shared__ int sA[S_];
    if (tid < 32) burstmask[tid] = ws[WS_BURSTMASK + tid];
    __syncthreads();

    const int wave = tid >> 6;
    const int lane = tid & 63;
    const int half = lane >> 5;
    const int l32  = lane & 31;
    const int sh   = half * 32;

    #pragma unroll
    for (int t = 0; t < 4; ++t) {
        const int seg = wave * 8 + t * 2 + half;
        const size_t base = ((size_t)cell * S_ + seg) * Y_ + (size_t)(l32 * 4);
        const int4   cv = *reinterpret_cast<const int4*>(conn + base);
        const float4 vv = *reinterpret_cast<const float4*>(vol + base);
        const float4 sv = *reinterpret_cast<const float4*>(cons + base);

        const int m0 = min(max(cv.x, 0), N_ - 1) >> 4;   // presyn column id
        const int m1 = min(max(cv.y, 0), N_ - 1) >> 4;
        const int m2 = min(max(cv.z, 0), N_ - 1) >> 4;
        const int m3 = min(max(cv.w, 0), N_ - 1) >> 4;
        const bool p0 = (burstmask[m0 >> 5] >> (m0 & 31)) & 1u;
        const bool p1 = (burstmask[m1 >> 5] >> (m1 & 31)) & 1u;
        const bool p2 = (burstmask[m2 >> 5] >> (m2 & 31)) & 1u;
        const bool p3 = (burstmask[m3 >> 5] >> (m3 & 31)) & 1u;
        const bool c0 = (vv.x > PERM_THR) || (sv.x > PERM_THR);
        const bool c1 = (vv.y > PERM_THR) || (sv.y > PERM_THR);
        const bool c2 = (vv.z > PERM_THR) || (sv.z > PERM_THR);
        const bool c3 = (vv.w > PERM_THR) || (sv.w > PERM_THR);

        const uint64_t ba0 = __ballot(p0 && c0), ba1 = __ballot(p1 && c1),
                       ba2 = __ballot(p2 && c2), ba3 = __ballot(p3 && c3);
        const int ac = __popc((unsigned)(ba0 >> sh)) + __popc((unsigned)(ba1 >> sh)) +
                       __popc((unsigned)(ba2 >> sh)) + __popc((unsigned)(ba3 >> sh));
        if (l32 == 0) sA[seg] = ac;
    }
    __syncthreads();
    if (tid == 0) {
        bool pred = false;
        #pragma unroll
        for (int s = 0; s < S_; ++s) pred |= (sA[s] >= ACT_THR);
        out_pred_next[cell] = pred ? 1.0f : 0.0f;
    }
}

// ---------------------------------------------------------------------------
extern "C" void kernel_launch(void* const* d_in, const int* in_sizes, int n_in,
                              void* d_out, int out_size, void* d_ws, size_t ws_size,
                              hipStream_t stream) {
    const int*   x    = (const int*)d_in[0];
    const int*   prev = (const int*)d_in[1];
    const int*   conn = (const int*)d_in[2];
    float*       vol  = (float*)d_in[3];        // updated in place (restored by harness)
    const float* cons = (const float*)d_in[4];
    float*    out = (float*)d_out;              // [0..N): new_active, [N..2N): pred_next, [2N]: acc
    unsigned* ws  = (unsigned*)d_ws;

    pack_kernel  <<<1,    256, 0, stream>>>(prev, ws);
    phase1_kernel<<<N_,   256, 0, stream>>>(conn, vol, cons, ws);
    column_kernel<<<C_/256, 256, 0, stream>>>(x, ws, out);
    learn_kernel <<<64,   256, 0, stream>>>(conn, vol, ws, out + 2 * N_);
    phase2_kernel<<<N_,   256, 0, stream>>>(conn, vol, cons, ws, out + N_);
}

// Round 2
// 670.394 us; speedup vs baseline: 1.0004x; 1.0004x over previous
//
#include <hip/hip_runtime.h>
#include <stdint.h>

#define C_ 1024
#define K_ 16
#define S_ 32
#define Y_ 128
#define N_ (C_ * K_)          // 16384 cells
#define ACT_THR 10
#define PERM_THR 0.5f
#define POT 0.1f              // LR * MOD
#define PUN 0.01f             // POT * 0.1

// ---- workspace layout (u32 indices) ----
#define WS_NUM_ACTIVE 0
#define WS_NUM_PRED   1
#define WS_NBURST     2
#define WS_LEARN_CNT  3
#define WS_PREV_ANY   4
#define WS_BURSTMASK  8        // 32 words  (1024 column bits)
#define WS_PREVMASK   64       // 512 words (16384 cell bits)
#define WS_CELLINFO   1024     // N words: pred(1b) | best_seg<<8 | best_overlap<<16
#define WS_LIST       (1024 + N_) // up to N winner-cell ids

#define P1_BLOCKS 2048         // 8 cells per block, 2 per wave

// ---------------------------------------------------------------------------
// Kernel 1: pack prev_active bits into ws bitmask, zero counters, prev_any.
// One block, 512 threads: thread w builds mask word w from 8 int4 loads.
// ---------------------------------------------------------------------------
__global__ __launch_bounds__(512) void pack_kernel(const int* __restrict__ prev,
                                                   unsigned* __restrict__ ws) {
    const int tid = threadIdx.x;
    if (tid < 64) ws[tid] = 0u;   // counters + burst mask
    __syncthreads();
    const int4* p = reinterpret_cast<const int4*>(prev + tid * 32);
    unsigned m = 0u;
    #pragma unroll
    for (int q = 0; q < 8; ++q) {
        const int4 v = p[q];
        m |= (v.x != 0 ? 1u : 0u) << (q * 4 + 0);
        m |= (v.y != 0 ? 1u : 0u) << (q * 4 + 1);
        m |= (v.z != 0 ? 1u : 0u) << (q * 4 + 2);
        m |= (v.w != 0 ? 1u : 0u) << (q * 4 + 3);
    }
    // NOTE: bit b of word w corresponds to cell w*32 + (bit position). The
    // int4 packing above maps element q*4+e to bit q*4+e — contiguous, correct.
    ws[WS_PREVMASK + tid] = m;
    const bool any = (__ballot(m != 0u) != 0ull);
    if ((tid & 63) == 0 && any) atomicOr(&ws[WS_PREV_ANY], 1u);
}

// ---------------------------------------------------------------------------
// Kernel 2: phase 1 — barrier-free streaming, one wave per cell (2 cells/wave).
// Half-wave per segment, 4 synapses/lane (16B loads), 1-deep prefetch.
// Running first-argmax via packed key (ov<<6)|(63-seg).
// ---------------------------------------------------------------------------
__global__ __launch_bounds__(256) void phase1_kernel(const int*   __restrict__ conn,
                                                     const float* __restrict__ vol,
                                                     const float* __restrict__ cons,
                                                     unsigned*    __restrict__ ws) {
    __shared__ unsigned prevmask[512];
    const int tid = threadIdx.x;
    for (int i = tid; i < 512; i += 256) prevmask[i] = ws[WS_PREVMASK + i];
    __syncthreads();

    const int wave = tid >> 6;
    const int lane = tid & 63;
    const int half = lane >> 5;
    const int l32  = lane & 31;
    const int sh   = half * 32;

    #pragma unroll 1
    for (int ci = 0; ci < 2; ++ci) {
        const int cell = blockIdx.x * 8 + wave + ci * 4;
        const size_t cellbase = (size_t)cell * (S_ * Y_) + (size_t)(l32 * 4);

        // prefetch iter 0 (segment = half)
        size_t a = cellbase + (size_t)half * Y_;
        int4   cv_n = *reinterpret_cast<const int4*>(conn + a);
        float4 vv_n = *reinterpret_cast<const float4*>(vol + a);
        float4 sv_n = *reinterpret_cast<const float4*>(cons + a);

        unsigned key = 0u;
        bool predf = false;

        #pragma unroll 2
        for (int i = 0; i < 16; ++i) {
            const int4   cv = cv_n;
            const float4 vv = vv_n;
            const float4 sv = sv_n;
            if (i < 15) {                       // issue next before processing
                const size_t nb = cellbase + (size_t)(2 * (i + 1) + half) * Y_;
                cv_n = *reinterpret_cast<const int4*>(conn + nb);
                vv_n = *reinterpret_cast<const float4*>(vol + nb);
                sv_n = *reinterpret_cast<const float4*>(cons + nb);
            }

            const int m0 = min(max(cv.x, 0), N_ - 1);
            const int m1 = min(max(cv.y, 0), N_ - 1);
            const int m2 = min(max(cv.z, 0), N_ - 1);
            const int m3 = min(max(cv.w, 0), N_ - 1);
            const bool p0 = (prevmask[m0 >> 5] >> (m0 & 31)) & 1u;
            const bool p1 = (prevmask[m1 >> 5] >> (m1 & 31)) & 1u;
            const bool p2 = (prevmask[m2 >> 5] >> (m2 & 31)) & 1u;
            const bool p3 = (prevmask[m3 >> 5] >> (m3 & 31)) & 1u;
            const bool c0 = (vv.x > PERM_THR) || (sv.x > PERM_THR);
            const bool c1 = (vv.y > PERM_THR) || (sv.y > PERM_THR);
            const bool c2 = (vv.z > PERM_THR) || (sv.z > PERM_THR);
            const bool c3 = (vv.w > PERM_THR) || (sv.w > PERM_THR);

            const uint64_t bp0 = __ballot(p0), bp1 = __ballot(p1),
                           bp2 = __ballot(p2), bp3 = __ballot(p3);
            const uint64_t ba0 = __ballot(p0 && c0), ba1 = __ballot(p1 && c1),
                           ba2 = __ballot(p2 && c2), ba3 = __ballot(p3 && c3);

            const int ov = __popc((unsigned)(bp0 >> sh)) + __popc((unsigned)(bp1 >> sh)) +
                           __popc((unsigned)(bp2 >> sh)) + __popc((unsigned)(bp3 >> sh));
            const int ac = __popc((unsigned)(ba0 >> sh)) + __popc((unsigned)(ba1 >> sh)) +
                           __popc((unsigned)(ba2 >> sh)) + __popc((unsigned)(ba3 >> sh));

            predf |= (ac >= ACT_THR);
            const int seg = 2 * i + half;
            const unsigned k2 = ((unsigned)ov << 6) | (unsigned)(63 - seg);
            key = max(key, k2);                 // max(ov, then smallest seg) == first argmax
        }

        const unsigned okey = (unsigned)__shfl_xor((int)key, 32);
        const unsigned fkey = max(key, okey);
        const bool fpred = (__any(predf ? 1 : 0) != 0);
        if (lane == 0) {
            const int bo = (int)(fkey >> 6);
            const int bs = 63 - (int)(fkey & 63u);
            ws[WS_CELLINFO + cell] = (fpred ? 1u : 0u) | ((unsigned)bs << 8) | ((unsigned)bo << 16);
        }
    }
}

// ---------------------------------------------------------------------------
// Kernel 3: per-column logic — predicted / burst winner / new_active output,
// learn list, counters, burst-column bitmask.
// ---------------------------------------------------------------------------
__global__ __launch_bounds__(256) void column_kernel(const int* __restrict__ x,
                                                     unsigned*  __restrict__ ws,
                                                     float*     __restrict__ out_new_active) {
    const int c = blockIdx.x * 256 + threadIdx.x;
    if (c >= C_) return;
    const bool xa = (x[c] != 0);
    const int base = c * K_;

    unsigned info[K_];
    bool colpred = false;
    int bo = -1, bk = 0;
    #pragma unroll
    for (int k = 0; k < K_; ++k) {
        const unsigned inf = ws[WS_CELLINFO + base + k];
        info[k] = inf;
        if (inf & 1u) colpred = true;
        const int ov = (int)((inf >> 16) & 0xFFu);
        if (ov > bo) { bo = ov; bk = k; }   // strict > keeps first (k,s) flat argmax
    }

    const bool burst = xa && !colpred;
    const float nav = burst ? 1.0f : 0.0f;
    #pragma unroll
    for (int k = 0; k < K_; ++k) out_new_active[base + k] = nav;

    if (xa) {
        atomicAdd(&ws[WS_NUM_ACTIVE], 1u);
        if (colpred) atomicAdd(&ws[WS_NUM_PRED], 1u);
    }
    if (burst) {
        atomicAdd(&ws[WS_NBURST], 1u);
        atomicOr(&ws[WS_BURSTMASK + (c >> 5)], 1u << (c & 31));
    }
    if (xa) {
        if (colpred) {
            #pragma unroll
            for (int k = 0; k < K_; ++k) {
                if (info[k] & 1u) {
                    const unsigned i = atomicAdd(&ws[WS_LEARN_CNT], 1u);
                    ws[WS_LIST + i] = (unsigned)(base + k);
                }
            }
        } else {
            const unsigned i = atomicAdd(&ws[WS_LEARN_CNT], 1u);
            ws[WS_LIST + i] = (unsigned)(base + bk);
        }
    }
}

// ---------------------------------------------------------------------------
// Kernel 4: learning — update volatile permanences on each winner's best
// segment (in place; harness restores inputs before every launch). Also acc.
// ---------------------------------------------------------------------------
__global__ __launch_bounds__(256) void learn_kernel(const int* __restrict__ conn,
                                                    float*     __restrict__ vol,
                                                    unsigned*  __restrict__ ws,
                                                    float*     __restrict__ out_acc) {
    __shared__ unsigned prevmask[512];
    const int tid = threadIdx.x;
    for (int i = tid; i < 512; i += 256) prevmask[i] = ws[WS_PREVMASK + i];
    __syncthreads();

    if (blockIdx.x == 0 && tid == 0) {
        const int na  = (int)ws[WS_NUM_ACTIVE];
        const int np_ = (int)ws[WS_NUM_PRED];
        out_acc[0] = (na > 0) ? ((float)np_ / (float)na) : 1.0f;
    }
    if (ws[WS_PREV_ANY] == 0u) return;   // torch skips learning if no prev activity

    const int cnt    = (int)ws[WS_LEARN_CNT];
    const int wave   = (blockIdx.x * 256 + tid) >> 6;
    const int lane   = tid & 63;
    const int nwaves = gridDim.x * 4;

    for (int e = wave; e < cnt; e += nwaves) {
        const int cell = (int)ws[WS_LIST + e];
        const int seg  = (int)((ws[WS_CELLINFO + cell] >> 8) & 0xFFu);
        const size_t base = ((size_t)cell * S_ + seg) * Y_ + (size_t)(lane * 2);
        const int2 cv = *reinterpret_cast<const int2*>(conn + base);
        float2 vv = *reinterpret_cast<const float2*>(vol + base);
        const int m0 = min(max(cv.x, 0), N_ - 1);
        const int m1 = min(max(cv.y, 0), N_ - 1);
        const bool p0 = (prevmask[m0 >> 5] >> (m0 & 31)) & 1u;
        const bool p1 = (prevmask[m1 >> 5] >> (m1 & 31)) & 1u;
        vv.x = fminf(fmaxf(vv.x + (p0 ? POT : -PUN), 0.0f), 1.0f);
        vv.y = fminf(fmaxf(vv.y + (p1 ? POT : -PUN), 0.0f), 1.0f);
        *reinterpret_cast<float2*>(vol + base) = vv;
    }
}

// ---------------------------------------------------------------------------
// Kernel 5: phase 2 — same skeleton as phase1; presyn = burst[col(m)].
// Block-level early exit (1 flag read per block) when no column bursts.
// ---------------------------------------------------------------------------
__global__ __launch_bounds__(256) void phase2_kernel(const int*   __restrict__ conn,
                                                     const float* __restrict__ vol,
                                                     const float* __restrict__ cons,
                                                     const unsigned* __restrict__ ws,
                                                     float* __restrict__ out_pred_next) {
    __shared__ unsigned nburst_s;
    __shared__ unsigned burstmask[32];
    const int tid = threadIdx.x;
    if (tid == 0) nburst_s = ws[WS_NBURST];
    if (tid >= 64 && tid < 96) burstmask[tid - 64] = ws[WS_BURSTMASK + (tid - 64)];
    __syncthreads();

    const int cbase = blockIdx.x * 8;
    if (nburst_s == 0u) {                       // uniform: no bursting columns
        if (tid < 8) out_pred_next[cbase + tid] = 0.0f;
        return;
    }

    const int wave = tid >> 6;
    const int lane = tid & 63;
    const int half = lane >> 5;
    const int l32  = lane & 31;
    const int sh   = half * 32;

    #pragma unroll 1
    for (int ci = 0; ci < 2; ++ci) {
        const int cell = cbase + wave + ci * 4;
        const size_t cellbase = (size_t)cell * (S_ * Y_) + (size_t)(l32 * 4);

        size_t a = cellbase + (size_t)half * Y_;
        int4   cv_n = *reinterpret_cast<const int4*>(conn + a);
        float4 vv_n = *reinterpret_cast<const float4*>(vol + a);
        float4 sv_n = *reinterpret_cast<const float4*>(cons + a);

        bool predf = false;

        #pragma unroll 2
        for (int i = 0; i < 16; ++i) {
            const int4   cv = cv_n;
            const float4 vv = vv_n;
            const float4 sv = sv_n;
            if (i < 15) {
                const size_t nb = cellbase + (size_t)(2 * (i + 1) + half) * Y_;
                cv_n = *reinterpret_cast<const int4*>(conn + nb);
                vv_n = *reinterpret_cast<const float4*>(vol + nb);
                sv_n = *reinterpret_cast<const float4*>(cons + nb);
            }

            const int m0 = min(max(cv.x, 0), N_ - 1) >> 4;   // presyn column id
            const int m1 = min(max(cv.y, 0), N_ - 1) >> 4;
            const int m2 = min(max(cv.z, 0), N_ - 1) >> 4;
            const int m3 = min(max(cv.w, 0), N_ - 1) >> 4;
            const bool p0 = (burstmask[m0 >> 5] >> (m0 & 31)) & 1u;
            const bool p1 = (burstmask[m1 >> 5] >> (m1 & 31)) & 1u;
            const bool p2 = (burstmask[m2 >> 5] >> (m2 & 31)) & 1u;
            const bool p3 = (burstmask[m3 >> 5] >> (m3 & 31)) & 1u;
            const bool c0 = (vv.x > PERM_THR) || (sv.x > PERM_THR);
            const bool c1 = (vv.y > PERM_THR) || (sv.y > PERM_THR);
            const bool c2 = (vv.z > PERM_THR) || (sv.z > PERM_THR);
            const bool c3 = (vv.w > PERM_THR) || (sv.w > PERM_THR);

            const uint64_t ba0 = __ballot(p0 && c0), ba1 = __ballot(p1 && c1),
                           ba2 = __ballot(p2 && c2), ba3 = __ballot(p3 && c3);
            const int ac = __popc((unsigned)(ba0 >> sh)) + __popc((unsigned)(ba1 >> sh)) +
                           __popc((unsigned)(ba2 >> sh)) + __popc((unsigned)(ba3 >> sh));
            predf |= (ac >= ACT_THR);
        }

        const bool fpred = (__any(predf ? 1 : 0) != 0);
        if (lane == 0) out_pred_next[cell] = fpred ? 1.0f : 0.0f;
    }
}

// ---------------------------------------------------------------------------
extern "C" void kernel_launch(void* const* d_in, const int* in_sizes, int n_in,
                              void* d_out, int out_size, void* d_ws, size_t ws_size,
                              hipStream_t stream) {
    const int*   x    = (const int*)d_in[0];
    const int*   prev = (const int*)d_in[1];
    const int*   conn = (const int*)d_in[2];
    float*       vol  = (float*)d_in[3];        // updated in place (restored by harness)
    const float* cons = (const float*)d_in[4];
    float*    out = (float*)d_out;              // [0..N): new_active, [N..2N): pred_next, [2N]: acc
    unsigned* ws  = (unsigned*)d_ws;

    pack_kernel  <<<1,        512, 0, stream>>>(prev, ws);
    phase1_kernel<<<P1_BLOCKS, 256, 0, stream>>>(conn, vol, cons, ws);
    column_kernel<<<C_ / 256,  256, 0, stream>>>(x, ws, out);
    learn_kernel <<<64,        256, 0, stream>>>(conn, vol, ws, out + 2 * N_);
    phase2_kernel<<<P1_BLOCKS, 256, 0, stream>>>(conn, vol, cons, ws, out + N_);
}